// Round 13
// baseline (91.100 us; speedup 1.0000x reference)
//
#include <hip/hip_runtime.h>

// Hawkes log-likelihood, D=1024 dims, M=32768 events, BETA=1.
//
// lam_i = mu[d_i] + sum_{j<i} alpha[d_i,d_j] * exp(t_j - t_i).
// Chunk events into NC=512 chunks of C=64:
//   cross-chunk: exp(t_c0 - t_i) * dot(alpha[d_i,:], S_c)
//   in-chunk:    one lane-parallel predicated gather step (C == wave size)
// S_c via TWO-LEVEL dimension-parallel scan; level-1 histogram+scan fused in
// LDS (k1); level-2 fixup S = Sl + Sg*cumdec fused into k_main's S load.
// TELESCOPING (R13): cumdec[c] = exp(t[g*2048] - t[c*64]) computed inline in
// k_main; Pg[g] = exp(T_g - T_{g+1}) from 17 boundary loads in k_mid.
// Compensator: contrib[j] histogram partials built in k1's fused role (LDS,
// multi-block); comp = sum_j colsum[j]*contrib[j] folded into k_mid's colred
// blocks (colsum never leaves LDS). k_main carries ll only.
//
// Lessons: R2 — same-cacheline global atomics serialize -> zero global
// atomics. R5 — single-block LDS-atomic histogram = 43us on one CU ->
// contrib built per-group across 64 blocks. R6 — DEEP dependent-chain roles
// must not merge; SHALLOW roles safe (k_mid/k1 verified). R10 — bf16 alpha.
// R11/R12 — each dispatch gap ~4us; 4 dispatches total.
//
// ws floats: ab(bf16)[D*D] | Sl[NC*D] | mu[D] | P[256*D] | contrib_p[NG*D] |
//            comp_p[8] | llp[NB] | A[NG*D] | Sg[NG*D]   (~5.5MB)

#define D 1024
#define M 32768
#define C 64
#define NC (M / C)   /* 512 */
#define NB (NC * 8)  /* k_main blocks: 4096 */
#define NG 16        /* scan groups */
#define GC (NC / NG) /* 32 chunks per group */
#define TMAXV 1000.0f
#define EPSMU 1e-6f
#define EPSLOG 1e-8f

__device__ __forceinline__ float softplus(float x) {
    return (x > 0.0f) ? (x + log1pf(__expf(-x))) : log1pf(__expf(x));
}

// round-to-nearest-even fp32 -> bf16 (inputs are positive finite)
__device__ __forceinline__ unsigned short f2bf(float x) {
    unsigned u = __float_as_uint(x);
    return (unsigned short)((u + 0x7FFFu + ((u >> 16) & 1u)) >> 16);
}
__device__ __forceinline__ float bf2f(unsigned short h) {
    return __uint_as_float(((unsigned)h) << 16);
}

// Stage 1, disjoint block roles; ALL roles read only raw inputs:
//   b in [0,256):   softplus(alpha) 4-row tile -> bf16 ab + fp32 colsum partial P
//   b == 256:       mu = softplus(log_mu) + eps
//   b in [257,321): fused level-1: per-chunk LDS histogram + LDS scan
//                   (16 groups x 4 dim-slices; writes Sl, aggregate A, and
//                    compensator-contrib partials contrib_p[g][slice])
__global__ void k1(const float* __restrict__ t_ev, const int* __restrict__ marks,
                   const float* __restrict__ log_alpha, const float* __restrict__ log_mu,
                   unsigned short* __restrict__ ab, float* __restrict__ mu,
                   float* __restrict__ P, float* __restrict__ Sl, float* __restrict__ A,
                   float* __restrict__ contrib_p) {
    __shared__ float Lh[GC * 256];  // 32 KB (fused role only)
    __shared__ float Ch[256];       // contrib slice
    __shared__ float dec[GC];
    __shared__ float tns[GC];
    int t = threadIdx.x;
    int b = blockIdx.x;

    if (b < 256) {
        int r0 = b * 4;
        float4 cs = {0.f, 0.f, 0.f, 0.f};
        for (int r = 0; r < 4; ++r) {
            const float4* src = (const float4*)(log_alpha + (size_t)(r0 + r) * D);
            float4 v = src[t];
            float4 a;
            a.x = softplus(v.x);
            a.y = softplus(v.y);
            a.z = softplus(v.z);
            a.w = softplus(v.w);
            cs.x += a.x; cs.y += a.y; cs.z += a.z; cs.w += a.w;
            ushort4 h;
            h.x = f2bf(a.x); h.y = f2bf(a.y); h.z = f2bf(a.z); h.w = f2bf(a.w);
            ((ushort4*)(ab + (size_t)(r0 + r) * D))[t] = h;
        }
        ((float4*)(P + (size_t)b * D))[t] = cs;  // P[b][col], col = 4t+j
    } else if (b == 256) {
#pragma unroll
        for (int q = 0; q < 4; ++q) {
            int k = t + 256 * q;
            mu[k] = softplus(log_mu[k]) + EPSMU;
        }
    } else {
        int fb = b - 257;            // 0..63
        int g = fb >> 2, db = fb & 3;
#pragma unroll
        for (int q = 0; q < GC; ++q) Lh[q * 256 + t] = 0.0f;
        Ch[t] = 0.0f;
        if (t < GC) {
            int gc = g * GC + t;
            float tn = (gc + 1 < NC) ? t_ev[(gc + 1) * C] : t_ev[M - 1];
            tns[t] = tn;
            dec[t] = (gc + 1 < NC) ? __expf(t_ev[gc * C] - tn) : 1.0f;
        }
        __syncthreads();
        int base = g * (GC * C);  // 2048 events per group
#pragma unroll
        for (int it = 0; it < 8; ++it) {
            int e = it * 256 + t;
            float te = t_ev[base + e];
            int m = marks[base + e];
            int lc = e >> 6;
            int ml = m - db * 256;
            if ((unsigned)ml < 256u) {
                atomicAdd(&Lh[lc * 256 + ml], __expf(te - tns[lc]));
                atomicAdd(&Ch[ml], 1.0f - __expf(te - TMAXV));
            }
        }
        __syncthreads();
        int k = db * 256 + t;
        contrib_p[(size_t)g * D + k] = Ch[t];
        float S = 0.0f;
        for (int lc = 0; lc < GC; ++lc) {
            Sl[(size_t)(g * GC + lc) * D + k] = S;
            S = S * dec[lc] + Lh[lc * 256 + t];
        }
        A[(size_t)g * D + k] = S;
    }
}

// Merged mid-stage, 9 blocks x 1024 threads (both roles SHALLOW):
//   blocks 0..7: colsum (in LDS) for 128 cols + comp_p[b] = sum colsum*contrib
//   block 8:     level-2 scan over 16 group aggregates (telescoped Pg)
__global__ void k_mid(const float* __restrict__ P, const float* __restrict__ contrib_p,
                      const float* __restrict__ t_ev, const float* __restrict__ A,
                      float* __restrict__ Sg, float* __restrict__ comp_p) {
    int t = threadIdx.x;
    if (blockIdx.x < 8) {
        __shared__ float red[8][128];
        __shared__ float pr[128];
        int colL = t & 127, seg = t >> 7;  // 8 segs x 128 cols
        int col = blockIdx.x * 128 + colL;
        float s = 0.0f;
#pragma unroll
        for (int j = 0; j < 32; ++j)
            s += P[(size_t)(seg * 32 + j) * D + col];
        red[seg][colL] = s;
        __syncthreads();
        if (t < 128) {
            float v = 0.0f;
#pragma unroll
            for (int k = 0; k < 8; ++k) v += red[k][t];     // colsum[col]
            float cs = 0.0f;
#pragma unroll
            for (int g = 0; g < NG; ++g) cs += contrib_p[(size_t)g * D + col];
            pr[t] = v * cs;
        }
        __syncthreads();
        for (int off = 64; off > 0; off >>= 1) {
            if (t < off) pr[t] += pr[t + off];
            __syncthreads();
        }
        if (t == 0) comp_p[blockIdx.x] = pr[0];
    } else {
        __shared__ float Pg[NG];
        if (t < NG) {
            float Tg = t_ev[t * (GC * C)];
            float Tn = (t < NG - 1) ? t_ev[(t + 1) * (GC * C)] : t_ev[M - 1];
            Pg[t] = __expf(Tg - Tn);  // Pg[15] unused by the scan
        }
        __syncthreads();
        float a[NG];
#pragma unroll
        for (int g2 = 0; g2 < NG; ++g2) a[g2] = A[(size_t)g2 * D + t];
        float S = 0.0f;
#pragma unroll
        for (int g2 = 0; g2 < NG; ++g2) {
            Sg[(size_t)g2 * D + t] = S;
            S = S * Pg[g2] + a[g2];
        }
    }
}

// main: 8 blocks per chunk (8 events each, 2 per wave), fused scan fixup with
// inline telescoped cumdec. ll partials only; no global atomics.
__launch_bounds__(256)
__global__ void k_main(const float* __restrict__ t_ev, const int* __restrict__ marks,
                       const unsigned short* __restrict__ ab, const float* __restrict__ mu,
                       const float* __restrict__ Sl, const float* __restrict__ Sg,
                       float* __restrict__ llp) {
    __shared__ float S_lds[D];
    __shared__ float t_lds[C];
    __shared__ int d_lds[C];
    __shared__ float red[4];
    int t = threadIdx.x;
    int c = blockIdx.x >> 3, sub = blockIdx.x & 7;
    int g = c >> 5;
    // telescoped cumdec: product of chunk decays from group start to chunk c
    float cd = __expf(t_ev[(size_t)g * (GC * C)] - t_ev[(size_t)c * C]);
#pragma unroll
    for (int q = 0; q < 4; ++q) {
        int k = t + 256 * q;
        S_lds[k] = Sl[(size_t)c * D + k] + Sg[(size_t)g * D + k] * cd;
    }
    if (t < C) {
        t_lds[t] = t_ev[c * C + t];
        d_lds[t] = marks[c * C + t];
    }
    __syncthreads();
    int wave = t >> 6, lane = t & 63;
    float t0 = t_lds[0];
    float ll_acc = 0.0f;
#pragma unroll
    for (int i = sub * 8 + wave; i < sub * 8 + 8; i += 4) {
        int row = d_lds[i];
        float ti = t_lds[i];
        float mu_r = mu[row];
        const uint4* arow = (const uint4*)(ab + (size_t)row * D);
        float acc_dot = 0.0f;
#pragma unroll
        for (int u = 0; u < 2; ++u) {
            uint4 pk = arow[2 * lane + u];  // 8 bf16: cols 16*lane+8u .. +7
            const float4* sp = (const float4*)(S_lds + 16 * lane + 8 * u);
            float4 s0 = sp[0], s1 = sp[1];
            acc_dot += __uint_as_float(pk.x << 16) * s0.x
                     + __uint_as_float(pk.x & 0xFFFF0000u) * s0.y
                     + __uint_as_float(pk.y << 16) * s0.z
                     + __uint_as_float(pk.y & 0xFFFF0000u) * s0.w
                     + __uint_as_float(pk.z << 16) * s1.x
                     + __uint_as_float(pk.z & 0xFFFF0000u) * s1.y
                     + __uint_as_float(pk.w << 16) * s1.z
                     + __uint_as_float(pk.w & 0xFFFF0000u) * s1.w;
        }
        float part = acc_dot * __expf(t0 - ti);
        if (lane < i) {
            part += bf2f(ab[(size_t)row * D + d_lds[lane]]) * __expf(t_lds[lane] - ti);
        }
#pragma unroll
        for (int off = 32; off > 0; off >>= 1) part += __shfl_xor(part, off);
        if (lane == 0) ll_acc += __logf(mu_r + part + EPSLOG);
    }
    if (lane == 0) red[wave] = ll_acc;
    __syncthreads();
    if (t == 0) llp[blockIdx.x] = red[0] + red[1] + red[2] + red[3];
}

// final: out = sum(llp) - (T*sum(mu) + sum(comp_p)). 1 block, 1024 threads.
__global__ void k_final(const float* __restrict__ llp, const float* __restrict__ comp_p,
                        const float* __restrict__ mu, float* __restrict__ out) {
    __shared__ float r_ll[1024], r_cm[1024], r_mu[1024];
    int t = threadIdx.x;
    float sll = 0.0f;
#pragma unroll
    for (int j = 0; j < 4; ++j) sll += llp[t + 1024 * j];
    r_ll[t] = sll;
    r_cm[t] = (t < 8) ? comp_p[t] : 0.0f;
    r_mu[t] = mu[t];
    __syncthreads();
    for (int off = 512; off > 0; off >>= 1) {
        if (t < off) {
            r_ll[t] += r_ll[t + off];
            r_cm[t] += r_cm[t + off];
            r_mu[t] += r_mu[t + off];
        }
        __syncthreads();
    }
    if (t == 0) out[0] = r_ll[0] - (TMAXV * r_mu[0] + r_cm[0]);
}

extern "C" void kernel_launch(void* const* d_in, const int* in_sizes, int n_in,
                              void* d_out, int out_size, void* d_ws, size_t ws_size,
                              hipStream_t stream) {
    const float* t_ev = (const float*)d_in[0];
    const int* marks = (const int*)d_in[1];
    const float* log_mu = (const float*)d_in[2];
    const float* log_alpha = (const float*)d_in[3];
    float* out = (float*)d_out;

    float* w = (float*)d_ws;
    unsigned short* ab = (unsigned short*)w;        // D*D bf16 = D*D/2 floats
    float* Sl = w + (size_t)D * D / 2;              // NC*D
    float* mu = Sl + (size_t)NC * D;                // D
    float* P = mu + D;                              // 256*D
    float* contrib_p = P + (size_t)256 * D;         // NG*D
    float* comp_p = contrib_p + (size_t)NG * D;     // 8
    float* llp = comp_p + 8;                        // NB
    float* A = llp + NB;                            // NG*D
    float* Sg = A + (size_t)NG * D;                 // NG*D

    k1<<<321, 256, 0, stream>>>(t_ev, marks, log_alpha, log_mu, ab, mu, P, Sl, A, contrib_p);
    k_mid<<<9, 1024, 0, stream>>>(P, contrib_p, t_ev, A, Sg, comp_p);
    k_main<<<NB, 256, 0, stream>>>(t_ev, marks, ab, mu, Sl, Sg, llp);
    k_final<<<1, 1024, 0, stream>>>(llp, comp_p, mu, out);
}